// Round 13
// baseline (107.215 us; speedup 1.0000x reference)
//
#include <hip/hip_runtime.h>
#include <math.h>

#define EPS 1e-9f

constexpr int Bn = 1024, Dn = 512, Un = 512;
constexpr int BM = 64;      // rows of B per block (4x4 per thread)
constexpr int BU = 64;      // cols of U per block
constexpr int DK = 32;      // d's staged at once (32KB LDS)

typedef float v4f __attribute__((ext_vector_type(4)));

// XOR swizzle for sL columns (R6-proven: conflicts -> 0). Multiples of 8,
// preserves b128 alignment of 4-float groups.
__device__ __forceinline__ int swz(int d) { return ((d >> 2) & 3) << 3; }

template <int SPLITD, bool USE_WS>
__global__ __launch_bounds__(256, 4) void power_layer(
    const float* __restrict__ x, const float* __restrict__ w,
    const float* __restrict__ p, const float* __restrict__ bias,
    float* __restrict__ outp)
{
    constexpr int DPB    = Dn / SPLITD;   // 32 at SPLITD=16
    constexpr int NCHUNK = DPB / DK;      // 1 at SPLITD=16: NO K-loop, 1 barrier

    __shared__ float sL[DK][BM];   // Lenc = sign(neg)*(log2|x+eps|+64), swizzled cols
    __shared__ float sP[DK][BU];   // p
    __shared__ float sW[DK][BU];   // w
    __shared__ float sWX[DK][BU];  // odd(p) ? -w : w

    const int tid = threadIdx.x;
    const int tx  = tid & 15;
    const int ty  = tid >> 4;
    const int tx4 = tx * 4;
    const int ty4 = ty * 4;
    const int ub = blockIdx.x * BU;
    const int bb = blockIdx.y * BM;
    const int d0 = blockIdx.z * DPB;

    v4f acc[4] = {};   // 4 rows x 4 cols per thread

    for (int ch = 0; ch < NCHUNK; ++ch) {
        const int db = d0 + ch * DK;
        if (ch > 0) __syncthreads();

        // ---- stage x tile -> sL (64 rows x 32 d, transposed+swizzled) ----
        // 512 float4 loads, 2 per thread.
        {
            int t = tid;
            #pragma unroll
            for (int it = 0; it < 2; ++it, t += 256) {
                const int r  = t >> 3;            // 0..63
                const int dq = (t & 7) << 2;      // 0,4,...,28
                const float4 xv = *reinterpret_cast<const float4*>(
                    &x[(size_t)(bb + r) * Dn + db + dq]);
                const float* xs = reinterpret_cast<const float*>(&xv);
                #pragma unroll
                for (int j = 0; j < 4; ++j) {
                    const float xe = xs[j] + EPS;
                    const float La = __builtin_amdgcn_logf(fabsf(xe)) + 64.0f;
                    const int dd = dq + j;
                    sL[dd][r ^ swz(dd)] = (xe < 0.0f) ? -La : La;
                }
            }
        }
        // ---- stage p,w tiles (32 d x 64 u), 2 float4 per thread each ----
        {
            const int d  = tid >> 3;          // 0..31
            const int u8 = (tid & 7) << 3;    // 0,8,...,56
            const size_t gi = (size_t)(db + d) * Un + ub + u8;
            #pragma unroll
            for (int h = 0; h < 2; ++h) {
                const float4 pv = *reinterpret_cast<const float4*>(&p[gi + h * 4]);
                const float4 wv = *reinterpret_cast<const float4*>(&w[gi + h * 4]);
                const float* ps  = reinterpret_cast<const float*>(&pv);
                const float* wsv = reinterpret_cast<const float*>(&wv);
                float4 wxv;
                float* wxs = reinterpret_cast<float*>(&wxv);
                #pragma unroll
                for (int j = 0; j < 4; ++j) {
                    const bool odd = (fmodf(ps[j], 2.0f) != 0.0f);
                    wxs[j] = odd ? -wsv[j] : wsv[j];
                }
                *reinterpret_cast<float4*>(&sP[d][u8 + h * 4])  = pv;
                *reinterpret_cast<float4*>(&sW[d][u8 + h * 4])  = wv;
                *reinterpret_cast<float4*>(&sWX[d][u8 + h * 4]) = wxv;
            }
        }
        __syncthreads();   // the ONLY barrier (at SPLITD=16)

        // ---- inner loop: 4 b128 reads per d feed 16 elements/thread ----
        #pragma unroll 2
        for (int d = 0; d < DK; ++d) {
            const v4f Lv = *reinterpret_cast<const v4f*>(&sL[d][ty4 ^ swz(d)]);
            const v4f Pv = *reinterpret_cast<const v4f*>(&sP[d][tx4]);
            const v4f Wv = *reinterpret_cast<const v4f*>(&sW[d][tx4]);
            const v4f Xv = *reinterpret_cast<const v4f*>(&sWX[d][tx4]);

            float Ld[4];
            bool  ng[4];
            #pragma unroll
            for (int r = 0; r < 4; ++r) {
                Ld[r] = fabsf(Lv[r]) - 64.0f;
                ng[r] = Lv[r] < 0.0f;
            }

            // batch all 16 independent exps before any consumer
            v4f e[4];
            #pragma unroll
            for (int r = 0; r < 4; ++r) {
                const v4f t = Pv * Ld[r];         // v_pk_mul_f32 x2
                #pragma unroll
                for (int c = 0; c < 4; ++c)
                    e[r][c] = __builtin_amdgcn_exp2f(t[c]);
            }

            #pragma unroll
            for (int r = 0; r < 4; ++r) {
                v4f wsel;
                #pragma unroll
                for (int c = 0; c < 4; ++c)
                    wsel[c] = ng[r] ? Xv[c] : Wv[c];   // v_cndmask
                acc[r] = __builtin_elementwise_fma(wsel, e[r], acc[r]);  // v_pk_fma x2
            }
        }
    }

    if (USE_WS) {
        // plain coalesced partial stores: ws[z][b][u]
        float* dst = outp + ((size_t)blockIdx.z * Bn + bb + ty4) * Un + ub + tx4;
        #pragma unroll
        for (int r = 0; r < 4; ++r)
            *reinterpret_cast<v4f*>(dst + (size_t)r * Un) = acc[r];
    } else {
        if (blockIdx.z == 0) {
            const v4f bv = *reinterpret_cast<const v4f*>(&bias[ub + tx4]);
            #pragma unroll
            for (int r = 0; r < 4; ++r)
                acc[r] += bv;
        }
        #pragma unroll
        for (int r = 0; r < 4; ++r) {
            const int row = bb + ty4 + r;
            #pragma unroll
            for (int c = 0; c < 4; ++c)
                atomicAdd(&outp[(size_t)row * Un + ub + tx4 + c], acc[r][c]);
        }
    }
}

// out[b,u] = sum_z ws[z][b][u] + bias[u]   (float4 per thread)
template <int SPLITD>
__global__ __launch_bounds__(256) void reduce_ws(
    const float* __restrict__ ws, const float* __restrict__ bias,
    float* __restrict__ out)
{
    const int nf4 = (Bn * Un) / 4;   // 131072
    const int i = blockIdx.x * 256 + threadIdx.x;
    if (i >= nf4) return;
    const v4f* w4 = reinterpret_cast<const v4f*>(ws);
    v4f a = w4[i];
    #pragma unroll
    for (int z = 1; z < SPLITD; ++z)
        a += w4[(size_t)z * nf4 + i];
    a += reinterpret_cast<const v4f*>(bias)[i & (Un / 4 - 1)];
    reinterpret_cast<v4f*>(out)[i] = a;
}

extern "C" void kernel_launch(void* const* d_in, const int* in_sizes, int n_in,
                              void* d_out, int out_size, void* d_ws, size_t ws_size,
                              hipStream_t stream) {
    const float* x = (const float*)d_in[0];
    const float* w = (const float*)d_in[1];
    const float* p = (const float*)d_in[2];
    const float* b = (const float*)d_in[3];
    float* out = (float*)d_out;

    const size_t need16 = (size_t)16 * Bn * Un * sizeof(float);   // 32 MB
    const size_t need8  = (size_t)8  * Bn * Un * sizeof(float);   // 16 MB
    const dim3 blk(256);
    const dim3 rgrid((Bn * Un / 4 + 255) / 256);

    if (ws_size >= need16) {
        // 8 x 16 x 16 = 2048 blocks; NCHUNK=1 -> single-barrier kernel
        float* wsf = (float*)d_ws;
        power_layer<16, true><<<dim3(Un / BU, Bn / BM, 16), blk, 0, stream>>>(x, w, p, b, wsf);
        reduce_ws<16><<<rgrid, blk, 0, stream>>>(wsf, b, out);
    } else if (ws_size >= need8) {
        float* wsf = (float*)d_ws;
        power_layer<8, true><<<dim3(Un / BU, Bn / BM, 8), blk, 0, stream>>>(x, w, p, b, wsf);
        reduce_ws<8><<<rgrid, blk, 0, stream>>>(wsf, b, out);
    } else {
        hipMemsetAsync(out, 0, (size_t)out_size * sizeof(float), stream);
        power_layer<8, false><<<dim3(Un / BU, Bn / BM, 8), blk, 0, stream>>>(x, w, p, b, out);
    }
}

// Round 14
// 105.948 us; speedup vs baseline: 1.0120x; 1.0120x over previous
//
#include <hip/hip_runtime.h>
#include <math.h>

#define EPS 1e-9f

constexpr int Bn = 1024, Dn = 512, Un = 512;
constexpr int BM = 64;      // rows of B per block (4x4 per thread)
constexpr int BU = 64;      // cols of U per block
constexpr int DK = 16;      // k-chunk staged in LDS (16KB/block)

typedef float v4f __attribute__((ext_vector_type(4)));

// XOR swizzle for sL columns (R6-proven: conflicts -> 0). Multiples of 8,
// preserves b128 alignment of 4-float groups.
__device__ __forceinline__ int swz(int d) { return ((d >> 2) & 3) << 3; }

template <int SPLITD, bool USE_WS>
__global__ __launch_bounds__(256, 4) void power_layer(
    const float* __restrict__ x, const float* __restrict__ w,
    const float* __restrict__ p, const float* __restrict__ bias,
    float* __restrict__ outp)
{
    constexpr int DPB    = Dn / SPLITD;
    constexpr int NCHUNK = DPB / DK;

    __shared__ float sL[DK][BM];   // Lenc = sign(neg)*(log2|x+eps|+64), swizzled cols
    __shared__ float sP[DK][BU];   // p
    __shared__ float sW[DK][BU];   // w
    __shared__ float sWX[DK][BU];  // odd(p) ? -w : w

    const int tid = threadIdx.x;
    const int tx  = tid & 15;
    const int ty  = tid >> 4;
    const int tx4 = tx * 4;
    const int ty4 = ty * 4;
    const int ub = blockIdx.x * BU;
    const int bb = blockIdx.y * BM;
    const int d0 = blockIdx.z * DPB;

    v4f acc[4] = {};   // 4 rows x 4 cols per thread

    for (int ch = 0; ch < NCHUNK; ++ch) {
        const int db = d0 + ch * DK;

        // ---- stage x tile -> sL (64 rows x 16 d, transposed+swizzled) ----
        // 256 float4 loads, 1 per thread.
        {
            const int r  = tid >> 2;          // 0..63
            const int dq = (tid & 3) << 2;    // 0,4,8,12
            const float4 xv = *reinterpret_cast<const float4*>(
                &x[(size_t)(bb + r) * Dn + db + dq]);
            const float* xs = reinterpret_cast<const float*>(&xv);
            #pragma unroll
            for (int j = 0; j < 4; ++j) {
                const float xe = xs[j] + EPS;
                const float La = __builtin_amdgcn_logf(fabsf(xe)) + 64.0f;
                const int dd = dq + j;
                sL[dd][r ^ swz(dd)] = (xe < 0.0f) ? -La : La;
            }
        }
        // ---- stage p,w tiles (16 d x 64 u, natural layout, 1 float4/thread) ----
        {
            const int d  = tid >> 4;          // 0..15
            const int uq = (tid & 15) << 2;   // 0..60
            const size_t gi = (size_t)(db + d) * Un + ub + uq;
            const float4 pv = *reinterpret_cast<const float4*>(&p[gi]);
            const float4 wv = *reinterpret_cast<const float4*>(&w[gi]);
            const float* ps  = reinterpret_cast<const float*>(&pv);
            const float* wsv = reinterpret_cast<const float*>(&wv);
            float4 wxv;
            float* wxs = reinterpret_cast<float*>(&wxv);
            #pragma unroll
            for (int j = 0; j < 4; ++j) {
                const bool odd = (fmodf(ps[j], 2.0f) != 0.0f);
                wxs[j] = odd ? -wsv[j] : wsv[j];
            }
            *reinterpret_cast<float4*>(&sP[d][uq])  = pv;
            *reinterpret_cast<float4*>(&sW[d][uq])  = wv;
            *reinterpret_cast<float4*>(&sWX[d][uq]) = wxv;
        }
        __syncthreads();

        // ---- inner loop: 4 b128 reads per d feed 16 elements/thread ----
        #pragma unroll 2
        for (int d = 0; d < DK; ++d) {
            const v4f Lv = *reinterpret_cast<const v4f*>(&sL[d][ty4 ^ swz(d)]);
            const v4f Pv = *reinterpret_cast<const v4f*>(&sP[d][tx4]);
            const v4f Wv = *reinterpret_cast<const v4f*>(&sW[d][tx4]);
            const v4f Xv = *reinterpret_cast<const v4f*>(&sWX[d][tx4]);

            float Ld[4];
            bool  ng[4];
            #pragma unroll
            for (int r = 0; r < 4; ++r) {
                Ld[r] = fabsf(Lv[r]) - 64.0f;
                ng[r] = Lv[r] < 0.0f;
            }

            // batch all 16 independent exps before any consumer
            v4f e[4];
            #pragma unroll
            for (int r = 0; r < 4; ++r) {
                const v4f t = Pv * Ld[r];         // v_pk_mul_f32 x2
                #pragma unroll
                for (int c = 0; c < 4; ++c)
                    e[r][c] = __builtin_amdgcn_exp2f(t[c]);
            }

            #pragma unroll
            for (int r = 0; r < 4; ++r) {
                v4f wsel;
                #pragma unroll
                for (int c = 0; c < 4; ++c)
                    wsel[c] = ng[r] ? Xv[c] : Wv[c];   // v_cndmask
                acc[r] = __builtin_elementwise_fma(wsel, e[r], acc[r]);  // v_pk_fma x2
            }
        }
        __syncthreads();
    }

    if (USE_WS) {
        // plain coalesced partial stores: ws[z][b][u]
        float* dst = outp + ((size_t)blockIdx.z * Bn + bb + ty4) * Un + ub + tx4;
        #pragma unroll
        for (int r = 0; r < 4; ++r)
            *reinterpret_cast<v4f*>(dst + (size_t)r * Un) = acc[r];
    } else {
        if (blockIdx.z == 0) {
            const v4f bv = *reinterpret_cast<const v4f*>(&bias[ub + tx4]);
            #pragma unroll
            for (int r = 0; r < 4; ++r)
                acc[r] += bv;
        }
        #pragma unroll
        for (int r = 0; r < 4; ++r) {
            const int row = bb + ty4 + r;
            #pragma unroll
            for (int c = 0; c < 4; ++c)
                atomicAdd(&outp[(size_t)row * Un + ub + tx4 + c], acc[r][c]);
        }
    }
}

// out[b,u] = sum_z ws[z][b][u] + bias[u]   (float4 per thread)
template <int SPLITD>
__global__ __launch_bounds__(256) void reduce_ws(
    const float* __restrict__ ws, const float* __restrict__ bias,
    float* __restrict__ out)
{
    const int nf4 = (Bn * Un) / 4;   // 131072
    const int i = blockIdx.x * 256 + threadIdx.x;
    if (i >= nf4) return;
    const v4f* w4 = reinterpret_cast<const v4f*>(ws);
    v4f a = w4[i];
    #pragma unroll
    for (int z = 1; z < SPLITD; ++z)
        a += w4[(size_t)z * nf4 + i];
    a += reinterpret_cast<const v4f*>(bias)[i & (Un / 4 - 1)];
    reinterpret_cast<v4f*>(out)[i] = a;
}

extern "C" void kernel_launch(void* const* d_in, const int* in_sizes, int n_in,
                              void* d_out, int out_size, void* d_ws, size_t ws_size,
                              hipStream_t stream) {
    const float* x = (const float*)d_in[0];
    const float* w = (const float*)d_in[1];
    const float* p = (const float*)d_in[2];
    const float* b = (const float*)d_in[3];
    float* out = (float*)d_out;

    const size_t need16 = (size_t)16 * Bn * Un * sizeof(float);   // 32 MB
    const size_t need8  = (size_t)8  * Bn * Un * sizeof(float);   // 16 MB
    const dim3 blk(256);
    const dim3 rgrid((Bn * Un / 4 + 255) / 256);

    if (ws_size >= need16) {
        // 8 x 16 x 16 = 2048 blocks
        float* wsf = (float*)d_ws;
        power_layer<16, true><<<dim3(Un / BU, Bn / BM, 16), blk, 0, stream>>>(x, w, p, b, wsf);
        reduce_ws<16><<<rgrid, blk, 0, stream>>>(wsf, b, out);
    } else if (ws_size >= need8) {
        float* wsf = (float*)d_ws;
        power_layer<8, true><<<dim3(Un / BU, Bn / BM, 8), blk, 0, stream>>>(x, w, p, b, wsf);
        reduce_ws<8><<<rgrid, blk, 0, stream>>>(wsf, b, out);
    } else {
        hipMemsetAsync(out, 0, (size_t)out_size * sizeof(float), stream);
        power_layer<8, false><<<dim3(Un / BU, Bn / BM, 8), blk, 0, stream>>>(x, w, p, b, out);
    }
}